// Round 2
// baseline (4560.072 us; speedup 1.0000x reference)
//
#include <hip/hip_runtime.h>
#include <stddef.h>

// Problem constants (AnatomicalTextEnhancer): B=16, R=29, D=512, N=20000, k=5
#define B_ 16
#define R_ 29
#define D_ 512
#define N_ 20000
#define K_ 5
#define TILE 1024
#define NBLK2 ((N_ + TILE - 1) / TILE)     // 20 n-tiles per r
#define GPW (NBLK2 * 4)                     // candidate groups per (r,b): 80
#define NEG_MASK (-1.0e9f)
#define SENT (-3.0e38f)

// ---------------------------------------------------------------------------
// Kernel 1: L2-normalize queries, write transposed layout qn[r][b][d]
// ---------------------------------------------------------------------------
__global__ __launch_bounds__(64) void knorm_kernel(const float* __restrict__ q,
                                                   float* __restrict__ qn) {
    int pair = blockIdx.x;          // 0 .. B*R-1
    int b = pair / R_;
    int r = pair % R_;
    int lane = threadIdx.x;
    const float4* src = (const float4*)(q + ((size_t)(b * R_ + r)) * D_);
    float4 x0 = src[lane * 2];
    float4 x1 = src[lane * 2 + 1];
    float ss = x0.x * x0.x + x0.y * x0.y + x0.z * x0.z + x0.w * x0.w +
               x1.x * x1.x + x1.y * x1.y + x1.z * x1.z + x1.w * x1.w;
#pragma unroll
    for (int off = 32; off; off >>= 1) ss += __shfl_xor(ss, off);
    float inv = 1.0f / fmaxf(sqrtf(ss), 1e-12f);
    float4 y0, y1;
    y0.x = x0.x * inv; y0.y = x0.y * inv; y0.z = x0.z * inv; y0.w = x0.w * inv;
    y1.x = x1.x * inv; y1.y = x1.y * inv; y1.z = x1.z * inv; y1.w = x1.w * inv;
    float4* dst = (float4*)(qn + ((size_t)(r * B_ + b)) * D_);
    dst[lane * 2] = y0;
    dst[lane * 2 + 1] = y1;
}

// ---------------------------------------------------------------------------
// Kernel 2: streaming register-tiled sims. One block = (r, 1024-row tile).
// Each thread owns 4 rows (stride 256), accumulates vs all 16 b.
// q panel in LDS (broadcast reads); kb streamed straight from global.
// No barriers in the main loop.
// ---------------------------------------------------------------------------
__global__ __launch_bounds__(256, 4) void ksim_kernel(const float* __restrict__ kb,
                                                      const float* __restrict__ qn,
                                                      const int* __restrict__ qid,
                                                      const int* __restrict__ kbid,
                                                      float* __restrict__ pvals,
                                                      int* __restrict__ pidx) {
    __shared__ float4 qs[B_ * D_ / 4];      // 32 KB: q panel for this r
    const int r = blockIdx.y;
    const int n0 = blockIdx.x * TILE;
    const int tid = threadIdx.x;

    // stage q panel once (coalesced), single barrier
    {
        const float4* src = (const float4*)(qn + (size_t)r * B_ * D_);
#pragma unroll
        for (int i = 0; i < 8; ++i) qs[tid + 256 * i] = src[tid + 256 * i];
    }
    __syncthreads();

    // this thread's 4 rows: n0 + tid + m*256 (lane-consecutive within a wave)
    int rowi[4];
    const float4* rowp[4];
    float acc[4][B_];
    float nrm[4];
#pragma unroll
    for (int m = 0; m < 4; ++m) {
        rowi[m] = n0 + tid + m * 256;
        int rc = rowi[m] < N_ ? rowi[m] : N_ - 1;   // clamp tail (masked later)
        rowp[m] = (const float4*)(kb + (size_t)r * N_ * D_ + (size_t)rc * D_);
        nrm[m] = 0.0f;
#pragma unroll
        for (int b = 0; b < B_; ++b) acc[m][b] = 0.0f;
    }

    // main loop: 32 iterations of 16 floats (64 B per row per iter)
    for (int c = 0; c < D_ / 16; ++c) {
#pragma unroll
        for (int j = 0; j < 4; ++j) {
            float4 kv[4];
#pragma unroll
            for (int m = 0; m < 4; ++m) kv[m] = rowp[m][c * 4 + j];
#pragma unroll
            for (int m = 0; m < 4; ++m)
                nrm[m] += kv[m].x * kv[m].x + kv[m].y * kv[m].y +
                          kv[m].z * kv[m].z + kv[m].w * kv[m].w;
#pragma unroll
            for (int b = 0; b < B_; ++b) {
                const float4 qv = qs[b * (D_ / 4) + c * 4 + j];  // broadcast
#pragma unroll
                for (int m = 0; m < 4; ++m)
                    acc[m][b] += kv[m].x * qv.x + kv[m].y * qv.y +
                                 kv[m].z * qv.z + kv[m].w * qv.w;
            }
        }
    }

    // finalize norms + masks
    float rinv[4];
    int myid[4];
#pragma unroll
    for (int m = 0; m < 4; ++m) {
        rinv[m] = 1.0f / fmaxf(sqrtf(nrm[m]), 1e-12f);
        myid[m] = (rowi[m] < N_) ? kbid[(size_t)r * N_ + rowi[m]] : -1;
    }

    // per-wave top-5 per b, straight from registers (no LDS)
    const int wv = tid >> 6;
    const int lane = tid & 63;
    for (int b = 0; b < B_; ++b) {
        const int qb = qid[b];              // uniform -> scalar load
        float v[4];
#pragma unroll
        for (int m = 0; m < 4; ++m) {
            float s = acc[m][b] * rinv[m];
            if (myid[m] == qb) s = NEG_MASK;
            if (rowi[m] >= N_) s = SENT;
            v[m] = s;
        }
        for (int k = 0; k < K_; ++k) {
            float bv = v[0];
            int bx = rowi[0];
#pragma unroll
            for (int m = 1; m < 4; ++m)
                if (v[m] > bv || (v[m] == bv && rowi[m] < bx)) { bv = v[m]; bx = rowi[m]; }
#pragma unroll
            for (int off = 32; off; off >>= 1) {
                float ov = __shfl_xor(bv, off);
                int ox = __shfl_xor(bx, off);
                if (ov > bv || (ov == bv && ox < bx)) { bv = ov; bx = ox; }
            }
            if (lane == 0) {
                size_t o = (((size_t)r * GPW + blockIdx.x * 4 + wv) * B_ + b) * K_ + k;
                pvals[o] = bv;
                pidx[o] = bx;
            }
#pragma unroll
            for (int m = 0; m < 4; ++m)
                if (rowi[m] == bx) v[m] = SENT;   // remove winner
        }
    }
}

// ---------------------------------------------------------------------------
// Kernel 3: reduce GPW*5 = 400 candidates per (b,r) to final top-5.
// d_out layout (all float32): scores[B][R] | vals[B][R][5] | idx[B][R][5]
// ---------------------------------------------------------------------------
__global__ __launch_bounds__(64) void ktop_kernel(const float* __restrict__ pvals,
                                                  const int* __restrict__ pidx,
                                                  float* __restrict__ out) {
    int pair = blockIdx.x;      // 0 .. B*R-1
    int b = pair / R_;
    int r = pair % R_;
    int lane = threadIdx.x;
    const int P = GPW * K_;     // 400
    float v[7];
    int ix[7];
#pragma unroll
    for (int j = 0; j < 7; ++j) {
        int c = lane + 64 * j;
        if (c < P) {
            int g = c / K_, kk = c % K_;
            size_t o = (((size_t)r * GPW + g) * B_ + b) * K_ + kk;
            v[j] = pvals[o];
            ix[j] = pidx[o];
        } else {
            v[j] = SENT;
            ix[j] = 0x7fffffff;
        }
    }
#pragma unroll
    for (int k = 0; k < K_; ++k) {
        float bv = v[0];
        int bx = ix[0];
#pragma unroll
        for (int j = 1; j < 7; ++j)
            if (v[j] > bv || (v[j] == bv && ix[j] < bx)) { bv = v[j]; bx = ix[j]; }
#pragma unroll
        for (int off = 32; off; off >>= 1) {
            float ov = __shfl_xor(bv, off);
            int ox = __shfl_xor(bx, off);
            if (ov > bv || (ov == bv && ox < bx)) { bv = ov; bx = ox; }
        }
        if (lane == 0) {
            int p = b * R_ + r;
            if (k == 0) out[p] = bv;                       // similarity_scores
            out[B_ * R_ + (size_t)p * K_ + k] = bv;        // top_vals
            out[B_ * R_ + (size_t)B_ * R_ * K_ + (size_t)p * K_ + k] = (float)bx; // top_idx
        }
#pragma unroll
        for (int j = 0; j < 7; ++j)
            if (ix[j] == bx) v[j] = SENT;
    }
}

// ---------------------------------------------------------------------------
extern "C" void kernel_launch(void* const* d_in, const int* in_sizes, int n_in,
                              void* d_out, int out_size, void* d_ws, size_t ws_size,
                              hipStream_t stream) {
    const float* q    = (const float*)d_in[0];   // [B,R,D] fp32
    const float* kb   = (const float*)d_in[1];   // [R,N,D] fp32
    const int*   qid  = (const int*)d_in[2];     // [B]
    const int*   kbid = (const int*)d_in[3];     // [R,N]
    float* out = (float*)d_out;

    float* qn    = (float*)d_ws;                             // R*B*D floats
    float* pvals = qn + (size_t)R_ * B_ * D_;                // R*GPW*B*K floats
    int*   pidx  = (int*)(pvals + (size_t)R_ * GPW * B_ * K_);

    knorm_kernel<<<B_ * R_, 64, 0, stream>>>(q, qn);
    dim3 g2(NBLK2, R_);
    ksim_kernel<<<g2, 256, 0, stream>>>(kb, qn, qid, kbid, pvals, pidx);
    ktop_kernel<<<B_ * R_, 64, 0, stream>>>(pvals, pidx, out);
}

// Round 3
// 628.137 us; speedup vs baseline: 7.2597x; 7.2597x over previous
//
#include <hip/hip_runtime.h>
#include <stddef.h>

// Problem constants (AnatomicalTextEnhancer): B=16, R=29, D=512, N=20000, k=5
#define B_ 16
#define R_ 29
#define D_ 512
#define N_ 20000
#define K_ 5
#define TILE 1024
#define NBLK2 ((N_ + TILE - 1) / TILE)     // 20 n-tiles per r
#define GPW (NBLK2 * 4)                     // candidate groups per (r,b): 80
#define NEG_MASK (-1.0e9f)
#define SENT (-3.0e38f)

// ---------------------------------------------------------------------------
// Kernel 1: L2-normalize queries, write transposed layout qn[r][b][d]
// ---------------------------------------------------------------------------
__global__ __launch_bounds__(64) void knorm_kernel(const float* __restrict__ q,
                                                   float* __restrict__ qn) {
    int pair = blockIdx.x;          // 0 .. B*R-1
    int b = pair / R_;
    int r = pair % R_;
    int lane = threadIdx.x;
    const float4* src = (const float4*)(q + ((size_t)(b * R_ + r)) * D_);
    float4 x0 = src[lane * 2];
    float4 x1 = src[lane * 2 + 1];
    float ss = x0.x * x0.x + x0.y * x0.y + x0.z * x0.z + x0.w * x0.w +
               x1.x * x1.x + x1.y * x1.y + x1.z * x1.z + x1.w * x1.w;
#pragma unroll
    for (int off = 32; off; off >>= 1) ss += __shfl_xor(ss, off);
    float inv = 1.0f / fmaxf(sqrtf(ss), 1e-12f);
    float4 y0, y1;
    y0.x = x0.x * inv; y0.y = x0.y * inv; y0.z = x0.z * inv; y0.w = x0.w * inv;
    y1.x = x1.x * inv; y1.y = x1.y * inv; y1.z = x1.z * inv; y1.w = x1.w * inv;
    float4* dst = (float4*)(qn + ((size_t)(r * B_ + b)) * D_);
    dst[lane * 2] = y0;
    dst[lane * 2 + 1] = y1;
}

// ---------------------------------------------------------------------------
// Kernel 2: streaming register-tiled sims. One block = (r, 1024-row tile).
// Each thread owns 4 rows (stride 256), accumulates vs all 16 b.
// q read via wave-uniform global loads -> SGPRs (SMEM pipe, L1-resident).
// kb streamed straight from global. No LDS, no barriers.
// ---------------------------------------------------------------------------
__global__ __launch_bounds__(256) void ksim_kernel(const float* __restrict__ kb,
                                                   const float* __restrict__ qn,
                                                   const int* __restrict__ qid,
                                                   const int* __restrict__ kbid,
                                                   float* __restrict__ pvals,
                                                   int* __restrict__ pidx) {
    const int r = blockIdx.y;
    const int n0 = blockIdx.x * TILE;
    const int tid = threadIdx.x;
    const float* qr = qn + (size_t)r * B_ * D_;   // block-uniform panel base

    // this thread's 4 rows: n0 + tid + m*256 (lane-consecutive within a wave)
    int rowi[4];
    const float4* rowp[4];
    float acc[4][B_];
    float nrm[4];
#pragma unroll
    for (int m = 0; m < 4; ++m) {
        rowi[m] = n0 + tid + m * 256;
        int rc = rowi[m] < N_ ? rowi[m] : N_ - 1;   // clamp tail (masked later)
        rowp[m] = (const float4*)(kb + (size_t)r * N_ * D_ + (size_t)rc * D_);
        nrm[m] = 0.0f;
#pragma unroll
        for (int b = 0; b < B_; ++b) acc[m][b] = 0.0f;
    }

    // main loop: 32 iterations of 16 floats (64 B per row per iter)
    for (int c = 0; c < D_ / 16; ++c) {
#pragma unroll
        for (int j = 0; j < 4; ++j) {
            float4 kv[4];
#pragma unroll
            for (int m = 0; m < 4; ++m) kv[m] = rowp[m][c * 4 + j];
#pragma unroll
            for (int m = 0; m < 4; ++m)
                nrm[m] += kv[m].x * kv[m].x + kv[m].y * kv[m].y +
                          kv[m].z * kv[m].z + kv[m].w * kv[m].w;
#pragma unroll
            for (int b = 0; b < B_; ++b) {
                // wave-uniform address -> scalar (s_load) into SGPRs
                const float4 qv = *(const float4*)(qr + b * D_ + c * 16 + j * 4);
#pragma unroll
                for (int m = 0; m < 4; ++m)
                    acc[m][b] += kv[m].x * qv.x + kv[m].y * qv.y +
                                 kv[m].z * qv.z + kv[m].w * qv.w;
            }
        }
    }

    // finalize norms + masks
    float rinv[4];
    int myid[4];
#pragma unroll
    for (int m = 0; m < 4; ++m) {
        rinv[m] = 1.0f / fmaxf(sqrtf(nrm[m]), 1e-12f);
        myid[m] = (rowi[m] < N_) ? kbid[(size_t)r * N_ + rowi[m]] : -1;
    }

    // per-wave top-5 per b, straight from registers (no LDS)
    const int wv = tid >> 6;
    const int lane = tid & 63;
    for (int b = 0; b < B_; ++b) {
        const int qb = qid[b];              // uniform -> scalar load
        float v[4];
#pragma unroll
        for (int m = 0; m < 4; ++m) {
            float s = acc[m][b] * rinv[m];
            if (myid[m] == qb) s = NEG_MASK;
            if (rowi[m] >= N_) s = SENT;
            v[m] = s;
        }
        for (int k = 0; k < K_; ++k) {
            float bv = v[0];
            int bx = rowi[0];
#pragma unroll
            for (int m = 1; m < 4; ++m)
                if (v[m] > bv || (v[m] == bv && rowi[m] < bx)) { bv = v[m]; bx = rowi[m]; }
#pragma unroll
            for (int off = 32; off; off >>= 1) {
                float ov = __shfl_xor(bv, off);
                int ox = __shfl_xor(bx, off);
                if (ov > bv || (ov == bv && ox < bx)) { bv = ov; bx = ox; }
            }
            if (lane == 0) {
                size_t o = (((size_t)r * GPW + blockIdx.x * 4 + wv) * B_ + b) * K_ + k;
                pvals[o] = bv;
                pidx[o] = bx;
            }
#pragma unroll
            for (int m = 0; m < 4; ++m)
                if (rowi[m] == bx) v[m] = SENT;   // remove winner
        }
    }
}

// ---------------------------------------------------------------------------
// Kernel 3: reduce GPW*5 = 400 candidates per (b,r) to final top-5.
// d_out layout (all float32): scores[B][R] | vals[B][R][5] | idx[B][R][5]
// ---------------------------------------------------------------------------
__global__ __launch_bounds__(64) void ktop_kernel(const float* __restrict__ pvals,
                                                  const int* __restrict__ pidx,
                                                  float* __restrict__ out) {
    int pair = blockIdx.x;      // 0 .. B*R-1
    int b = pair / R_;
    int r = pair % R_;
    int lane = threadIdx.x;
    const int P = GPW * K_;     // 400
    float v[7];
    int ix[7];
#pragma unroll
    for (int j = 0; j < 7; ++j) {
        int c = lane + 64 * j;
        if (c < P) {
            int g = c / K_, kk = c % K_;
            size_t o = (((size_t)r * GPW + g) * B_ + b) * K_ + kk;
            v[j] = pvals[o];
            ix[j] = pidx[o];
        } else {
            v[j] = SENT;
            ix[j] = 0x7fffffff;
        }
    }
#pragma unroll
    for (int k = 0; k < K_; ++k) {
        float bv = v[0];
        int bx = ix[0];
#pragma unroll
        for (int j = 1; j < 7; ++j)
            if (v[j] > bv || (v[j] == bv && ix[j] < bx)) { bv = v[j]; bx = ix[j]; }
#pragma unroll
        for (int off = 32; off; off >>= 1) {
            float ov = __shfl_xor(bv, off);
            int ox = __shfl_xor(bx, off);
            if (ov > bv || (ov == bv && ox < bx)) { bv = ov; bx = ox; }
        }
        if (lane == 0) {
            int p = b * R_ + r;
            if (k == 0) out[p] = bv;                       // similarity_scores
            out[B_ * R_ + (size_t)p * K_ + k] = bv;        // top_vals
            out[B_ * R_ + (size_t)B_ * R_ * K_ + (size_t)p * K_ + k] = (float)bx; // top_idx
        }
#pragma unroll
        for (int j = 0; j < 7; ++j)
            if (ix[j] == bx) v[j] = SENT;
    }
}

// ---------------------------------------------------------------------------
extern "C" void kernel_launch(void* const* d_in, const int* in_sizes, int n_in,
                              void* d_out, int out_size, void* d_ws, size_t ws_size,
                              hipStream_t stream) {
    const float* q    = (const float*)d_in[0];   // [B,R,D] fp32
    const float* kb   = (const float*)d_in[1];   // [R,N,D] fp32
    const int*   qid  = (const int*)d_in[2];     // [B]
    const int*   kbid = (const int*)d_in[3];     // [R,N]
    float* out = (float*)d_out;

    float* qn    = (float*)d_ws;                             // R*B*D floats
    float* pvals = qn + (size_t)R_ * B_ * D_;                // R*GPW*B*K floats
    int*   pidx  = (int*)(pvals + (size_t)R_ * GPW * B_ * K_);

    knorm_kernel<<<B_ * R_, 64, 0, stream>>>(q, qn);
    dim3 g2(NBLK2, R_);
    ksim_kernel<<<g2, 256, 0, stream>>>(kb, qn, qid, kbid, pvals, pidx);
    ktop_kernel<<<B_ * R_, 64, 0, stream>>>(pvals, pidx, out);
}

// Round 4
// 502.094 us; speedup vs baseline: 9.0821x; 1.2510x over previous
//
#include <hip/hip_runtime.h>
#include <stddef.h>

// Problem constants (AnatomicalTextEnhancer): B=16, R=29, D=512, N=20000, k=5
#define B_ 16
#define R_ 29
#define D_ 512
#define N_ 20000
#define K_ 5
#define TILE 256                          // rows per block
#define NT ((N_ + TILE - 1) / TILE)       // 79 tiles per r
#define NG (NT * 4)                       // candidate groups per (r,b): 316
#define PCAND (NG * K_)                   // candidates per (r,b): 1580
#define NEG_MASK (-1.0e9f)
#define SENT (-3.0e38f)
#define IXMAX 0x7fffffff

// ---------------------------------------------------------------------------
// Kernel 1: L2-normalize queries, write transposed layout qn[r][b][d]
// ---------------------------------------------------------------------------
__global__ __launch_bounds__(64) void knorm_kernel(const float* __restrict__ q,
                                                   float* __restrict__ qn) {
    int pair = blockIdx.x;          // 0 .. B*R-1
    int b = pair / R_;
    int r = pair % R_;
    int lane = threadIdx.x;
    const float4* src = (const float4*)(q + ((size_t)(b * R_ + r)) * D_);
    float4 x0 = src[lane * 2];
    float4 x1 = src[lane * 2 + 1];
    float ss = x0.x * x0.x + x0.y * x0.y + x0.z * x0.z + x0.w * x0.w +
               x1.x * x1.x + x1.y * x1.y + x1.z * x1.z + x1.w * x1.w;
#pragma unroll
    for (int off = 32; off; off >>= 1) ss += __shfl_xor(ss, off);
    float inv = 1.0f / fmaxf(sqrtf(ss), 1e-12f);
    float4 y0, y1;
    y0.x = x0.x * inv; y0.y = x0.y * inv; y0.z = x0.z * inv; y0.w = x0.w * inv;
    y1.x = x1.x * inv; y1.y = x1.y * inv; y1.z = x1.z * inv; y1.w = x1.w * inv;
    float4* dst = (float4*)(qn + ((size_t)(r * B_ + b)) * D_);
    dst[lane * 2] = y0;
    dst[lane * 2 + 1] = y1;
}

// ---------------------------------------------------------------------------
// Kernel 2: one block = (r, 256-row tile). Wave handles 64 rows:
// lane = 4*g + s; g in [0,16) row-group, s in [0,4) d-split.
// Lane accumulates rows {g, g+16, g+32, g+48} x all 16 b over d-chunks 4p+s.
// kb loads: 16 lines/instr (vs 64 row-per-lane). q: LDS broadcast reads.
// Dot totals reduced over the 4 s-lanes at the end (2 shfl_xor).
// ---------------------------------------------------------------------------
__global__ __launch_bounds__(256) void ksim_kernel(const float* __restrict__ kb,
                                                   const float* __restrict__ qn,
                                                   const int* __restrict__ qid,
                                                   const int* __restrict__ kbid,
                                                   float* __restrict__ pvals,
                                                   int* __restrict__ pidx) {
    __shared__ float4 qs[B_ * D_ / 4];    // 8192 float4 = 32 KB q panel
    const int r = blockIdx.y;
    const int n0 = blockIdx.x * TILE;
    const int tid = threadIdx.x;

    // stage q panel once (coalesced), single barrier
    {
        const float4* src = (const float4*)(qn + (size_t)r * B_ * D_);
#pragma unroll
        for (int i = 0; i < 32; ++i) qs[tid + 256 * i] = src[tid + 256 * i];
    }
    __syncthreads();

    const int wv = tid >> 6;
    const int lane = tid & 63;
    const int g = lane >> 2;              // row group 0..15
    const int s = lane & 3;               // d-split 0..3

    int rowi[4];
    const float4* rowp[4];
    float acc[4][B_];
    float nrm[4];
#pragma unroll
    for (int m = 0; m < 4; ++m) {
        rowi[m] = n0 + wv * 64 + g + m * 16;
        int rc = rowi[m] < N_ ? rowi[m] : N_ - 1;   // clamp tail (masked later)
        rowp[m] = (const float4*)(kb + (size_t)r * N_ * D_ + (size_t)rc * D_) + s;
        nrm[m] = 0.0f;
#pragma unroll
        for (int b = 0; b < B_; ++b) acc[m][b] = 0.0f;
    }

    // main loop: p = 0..31; this lane's chunk = float4 #(4p + s) of each row
    for (int p = 0; p < 32; ++p) {
        float4 kv[4];
#pragma unroll
        for (int m = 0; m < 4; ++m) kv[m] = rowp[m][p * 4];
#pragma unroll
        for (int m = 0; m < 4; ++m)
            nrm[m] += kv[m].x * kv[m].x + kv[m].y * kv[m].y +
                      kv[m].z * kv[m].z + kv[m].w * kv[m].w;
#pragma unroll
        for (int b = 0; b < B_; ++b) {
            const float4 qv = qs[b * 128 + p * 4 + s];   // 4 uniq addrs, bcast
#pragma unroll
            for (int m = 0; m < 4; ++m)
                acc[m][b] += kv[m].x * qv.x + kv[m].y * qv.y +
                             kv[m].z * qv.z + kv[m].w * qv.w;
        }
    }

    // reduce partial dots / norms across the 4 s-lanes (all lanes get totals)
#pragma unroll
    for (int m = 0; m < 4; ++m) {
        nrm[m] += __shfl_xor(nrm[m], 1);
        nrm[m] += __shfl_xor(nrm[m], 2);
#pragma unroll
        for (int b = 0; b < B_; ++b) {
            acc[m][b] += __shfl_xor(acc[m][b], 1);
            acc[m][b] += __shfl_xor(acc[m][b], 2);
        }
    }

    // finalize norms + masks
    float rinv[4];
    int myid[4];
#pragma unroll
    for (int m = 0; m < 4; ++m) {
        rinv[m] = 1.0f / fmaxf(sqrtf(nrm[m]), 1e-12f);
        myid[m] = (rowi[m] < N_) ? kbid[(size_t)r * N_ + rowi[m]] : -1;
    }

    // per-wave top-5 per b over its 64 rows (each row replicated in 4 s-lanes;
    // identical (val,idx) copies -> argmax + index-removal stay consistent)
    const int group = blockIdx.x * 4 + wv;
    for (int b = 0; b < B_; ++b) {
        const int qb = qid[b];            // uniform -> scalar load
        float v[4];
#pragma unroll
        for (int m = 0; m < 4; ++m) {
            float sv = acc[m][b] * rinv[m];
            if (myid[m] == qb) sv = NEG_MASK;
            if (rowi[m] >= N_) sv = SENT;
            v[m] = sv;
        }
        for (int k = 0; k < K_; ++k) {
            float bv = v[0];
            int bx = rowi[0];
#pragma unroll
            for (int m = 1; m < 4; ++m)
                if (v[m] > bv || (v[m] == bv && rowi[m] < bx)) { bv = v[m]; bx = rowi[m]; }
#pragma unroll
            for (int off = 32; off; off >>= 1) {
                float ov = __shfl_xor(bv, off);
                int ox = __shfl_xor(bx, off);
                if (ov > bv || (ov == bv && ox < bx)) { bv = ov; bx = ox; }
            }
            if (lane == 0) {
                size_t o = (((size_t)r * B_ + b) * NG + group) * K_ + k;
                pvals[o] = bv;
                pidx[o] = bx;
            }
#pragma unroll
            for (int m = 0; m < 4; ++m)
                if (rowi[m] == bx) v[m] = SENT;   // remove winner (all s-copies)
        }
    }
}

// ---------------------------------------------------------------------------
// Kernel 3: reduce 1580 candidates per (b,r) to final top-5.
// Per-lane running sorted top-5 (registers) + 5 shuffle-argmax extractions.
// d_out layout (all float32): scores[B][R] | vals[B][R][5] | idx[B][R][5]
// ---------------------------------------------------------------------------
__global__ __launch_bounds__(64) void ktop_kernel(const float* __restrict__ pvals,
                                                  const int* __restrict__ pidx,
                                                  float* __restrict__ out) {
    int pair = blockIdx.x;      // 0 .. B*R-1
    int b = pair / R_;
    int r = pair % R_;
    int lane = threadIdx.x;
    const float* pv = pvals + ((size_t)r * B_ + b) * PCAND;
    const int* px = pidx + ((size_t)r * B_ + b) * PCAND;

    float tv[5];
    int tx[5];
#pragma unroll
    for (int t = 0; t < 5; ++t) { tv[t] = SENT; tx[t] = IXMAX; }

    for (int j = 0; j < (PCAND + 63) / 64; ++j) {
        int c = lane + 64 * j;
        if (c < PCAND) {
            float v = pv[c];
            int ix = px[c];
            if (v > tv[4] || (v == tv[4] && ix < tx[4])) {
                tv[4] = v; tx[4] = ix;
#pragma unroll
                for (int t = 4; t > 0; --t)
                    if (tv[t] > tv[t - 1] ||
                        (tv[t] == tv[t - 1] && tx[t] < tx[t - 1])) {
                        float fv = tv[t]; tv[t] = tv[t - 1]; tv[t - 1] = fv;
                        int fx = tx[t]; tx[t] = tx[t - 1]; tx[t - 1] = fx;
                    }
            }
        }
    }

#pragma unroll
    for (int k = 0; k < K_; ++k) {
        float bv = tv[0];
        int bx = tx[0];
#pragma unroll
        for (int off = 32; off; off >>= 1) {
            float ov = __shfl_xor(bv, off);
            int ox = __shfl_xor(bx, off);
            if (ov > bv || (ov == bv && ox < bx)) { bv = ov; bx = ox; }
        }
        if (lane == 0) {
            int p = b * R_ + r;
            if (k == 0) out[p] = bv;                       // similarity_scores
            out[B_ * R_ + (size_t)p * K_ + k] = bv;        // top_vals
            out[B_ * R_ + (size_t)B_ * R_ * K_ + (size_t)p * K_ + k] = (float)bx; // top_idx
        }
        // remove winner from this lane's sorted list (forward shift)
        bool f0 = (tx[0] == bx);
        bool f1 = f0 || (tx[1] == bx);
        bool f2 = f1 || (tx[2] == bx);
        bool f3 = f2 || (tx[3] == bx);
        bool f4 = f3 || (tx[4] == bx);
        if (f0) { tv[0] = tv[1]; tx[0] = tx[1]; }
        if (f1) { tv[1] = tv[2]; tx[1] = tx[2]; }
        if (f2) { tv[2] = tv[3]; tx[2] = tx[3]; }
        if (f3) { tv[3] = tv[4]; tx[3] = tx[4]; }
        if (f4) { tv[4] = SENT; tx[4] = IXMAX; }
    }
}

// ---------------------------------------------------------------------------
extern "C" void kernel_launch(void* const* d_in, const int* in_sizes, int n_in,
                              void* d_out, int out_size, void* d_ws, size_t ws_size,
                              hipStream_t stream) {
    const float* q    = (const float*)d_in[0];   // [B,R,D] fp32
    const float* kb   = (const float*)d_in[1];   // [R,N,D] fp32
    const int*   qid  = (const int*)d_in[2];     // [B]
    const int*   kbid = (const int*)d_in[3];     // [R,N]
    float* out = (float*)d_out;

    float* qn    = (float*)d_ws;                             // R*B*D floats
    float* pvals = qn + (size_t)R_ * B_ * D_;                // R*B*NG*K floats
    int*   pidx  = (int*)(pvals + (size_t)R_ * B_ * NG * K_);

    knorm_kernel<<<B_ * R_, 64, 0, stream>>>(q, qn);
    dim3 g2(NT, R_);
    ksim_kernel<<<g2, 256, 0, stream>>>(kb, qn, qid, kbid, pvals, pidx);
    ktop_kernel<<<B_ * R_, 64, 0, stream>>>(pvals, pidx, out);
}